// Round 5
// baseline (2590.651 us; speedup 1.0000x reference)
//
#include <hip/hip_runtime.h>
#include <hip/hip_bf16.h>

#define TT 64
#define BB 4096
#define HH 256
#define BMb 16             // batches per block
#define NBLK (BB / BMb)    // 256 blocks -> 1 block/CU, 4 waves (1/SIMD)

typedef short bf16x8_t __attribute__((ext_vector_type(8)));
typedef float f32x4_t  __attribute__((ext_vector_type(4)));

// d_ws layout (byte offsets)
#define WS_WA_B   0u          // split bf16 weights: 2 layers*3 parts*8kt*16nt*64lane*8j shorts = 768 KB
#define WS_EMB_B  786432u     // emb f32
#define WS_REC_B  1048576u    // rec f32 [T][B][4], 4 MB

__device__ __forceinline__ float clip01f(float v) {
    return fminf(fmaxf(v, 0.0f), 1.0f);
}

__global__ __launch_bounds__(64) void setup_emb_kernel(float* __restrict__ emb) {
    int i = threadIdx.x;
    const double sigma = 64.0 / 10.0;
    const double c = 32.0;
    double d = ((double)i - c) / sigma;
    double e = exp(-0.5 * (d * d));
    double d0 = (0.0 - c) / sigma;
    double emin = exp(-0.5 * (d0 * d0));
    emb[i] = (float)((e - emin) / (1.0 - emin));
}

// Exact 3-way split w = hi + mid + lo into bf16 parts (residuals exact).
// Pre-swizzled to A-fragment order for mfma_f32_16x16x32_bf16:
// A[m=lane&15][k=(lane>>4)*8+j], flat = ((((layer*3+part)*8+kt)*16+ntile)*64+lane)*8+j
__global__ __launch_bounds__(256) void split_weights_kernel(
    const float* __restrict__ W_h, const float* __restrict__ W_h2,
    unsigned short* __restrict__ WA)
{
    int flat = blockIdx.x * 256 + threadIdx.x;     // < 393216
    int j     = flat & 7;
    int lane  = (flat >> 3) & 63;
    int ntile = (flat >> 9) & 15;
    int kt    = (flat >> 13) & 7;
    int rest  = flat >> 16;                        // 0..5
    int part  = rest % 3;
    int layer = rest / 3;
    int k = kt * 32 + (lane >> 4) * 8 + j;
    int n = ntile * 16 + (lane & 15);
    const float* W = layer ? W_h2 : W_h;           // row-major [n][k] = W[n*256+k]
    float w = W[n * HH + k];
    __hip_bfloat16 h = __float2bfloat16(w);
    float r1 = w - __bfloat162float(h);
    __hip_bfloat16 m = __float2bfloat16(r1);
    float r2 = r1 - __bfloat162float(m);
    __hip_bfloat16 l = __float2bfloat16(r2);
    __hip_bfloat16 v = (part == 0) ? h : ((part == 1) ? m : l);
    WA[flat] = *reinterpret_cast<unsigned short*>(&v);
}

union U16x8 { uint4 u; bf16x8_t v; };

// ---- 256-thread / 4-wave structure: wave w owns n-tiles {4w..4w+3}. ----
// Regalloc model (R1-R4 evidence): VGPR budget = 512 / (waves/EU implied by
// static LDS): floor(160/62KB)=2 blocks x 4 waves = 8 waves/CU = 2/EU -> 256
// VGPRs. The 24-slot depth-2 prefetch (96 VGPRs) + 4-tile state (~220 total)
// fits; at 512thr (budget 128) and 1024thr (budget 64) it spilled to scratch
// (WRITE_SIZE 135-188 MB, L2 thrash, 4-6 GB HBM fetch).
//
// STEPG: consume slot group G (4 tiles x parts 0,1,2 in order -> per-D
// accumulation order IDENTICAL to baseline -> bit-identical D), refill the
// group for kt+2 (or the next phase's kt0/kt1 at the last two steps).
#define STEPG(G, T0, T1, T2, T3, ktr, Bp, ktb) do {                            \
    U16x8 br_; br_.u = (Bp)[(ktb) * 64];            /* ds_read_b128 spikes */  \
    U16x8 c00, c01, c02, c10, c11, c12, c20, c21, c22, c30, c31, c32;          \
    c00.u = q##G##0a; c01.u = q##G##0b; c02.u = q##G##0c;                      \
    c10.u = q##G##1a; c11.u = q##G##1b; c12.u = q##G##1c;                      \
    c20.u = q##G##2a; c21.u = q##G##2b; c22.u = q##G##2c;                      \
    c30.u = q##G##3a; c31.u = q##G##3b; c32.u = q##G##3c;                      \
    q##G##0a = (T0)[(0 * 8 + (ktr)) * 1024];                                   \
    q##G##0b = (T0)[(1 * 8 + (ktr)) * 1024];                                   \
    q##G##0c = (T0)[(2 * 8 + (ktr)) * 1024];                                   \
    q##G##1a = (T1)[(0 * 8 + (ktr)) * 1024];                                   \
    q##G##1b = (T1)[(1 * 8 + (ktr)) * 1024];                                   \
    q##G##1c = (T1)[(2 * 8 + (ktr)) * 1024];                                   \
    q##G##2a = (T2)[(0 * 8 + (ktr)) * 1024];                                   \
    q##G##2b = (T2)[(1 * 8 + (ktr)) * 1024];                                   \
    q##G##2c = (T2)[(2 * 8 + (ktr)) * 1024];                                   \
    q##G##3a = (T3)[(0 * 8 + (ktr)) * 1024];                                   \
    q##G##3b = (T3)[(1 * 8 + (ktr)) * 1024];                                   \
    q##G##3c = (T3)[(2 * 8 + (ktr)) * 1024];                                   \
    D0 = __builtin_amdgcn_mfma_f32_16x16x32_bf16(c00.v, br_.v, D0, 0, 0, 0);   \
    D0 = __builtin_amdgcn_mfma_f32_16x16x32_bf16(c01.v, br_.v, D0, 0, 0, 0);   \
    D0 = __builtin_amdgcn_mfma_f32_16x16x32_bf16(c02.v, br_.v, D0, 0, 0, 0);   \
    D1 = __builtin_amdgcn_mfma_f32_16x16x32_bf16(c10.v, br_.v, D1, 0, 0, 0);   \
    D1 = __builtin_amdgcn_mfma_f32_16x16x32_bf16(c11.v, br_.v, D1, 0, 0, 0);   \
    D1 = __builtin_amdgcn_mfma_f32_16x16x32_bf16(c12.v, br_.v, D1, 0, 0, 0);   \
    D2 = __builtin_amdgcn_mfma_f32_16x16x32_bf16(c20.v, br_.v, D2, 0, 0, 0);   \
    D2 = __builtin_amdgcn_mfma_f32_16x16x32_bf16(c21.v, br_.v, D2, 0, 0, 0);   \
    D2 = __builtin_amdgcn_mfma_f32_16x16x32_bf16(c22.v, br_.v, D2, 0, 0, 0);   \
    D3 = __builtin_amdgcn_mfma_f32_16x16x32_bf16(c30.v, br_.v, D3, 0, 0, 0);   \
    D3 = __builtin_amdgcn_mfma_f32_16x16x32_bf16(c31.v, br_.v, D3, 0, 0, 0);   \
    D3 = __builtin_amdgcn_mfma_f32_16x16x32_bf16(c32.v, br_.v, D3, 0, 0, 0);   \
} while (0)

// kt = 0..7 ascending; enters with group0=kt0, group1=kt1 (issued >= 2 steps
// earlier); steps 0..5 refill kt+2, steps 6..7 refill NEXT phase's kt0/kt1.
#define MFMA_PHASE4(C0, C1, C2, C3, N0, N1, N2, N3, Bp) do {                   \
    STEPG(0, C0, C1, C2, C3, 2, Bp, 0);                                        \
    STEPG(1, C0, C1, C2, C3, 3, Bp, 1);                                        \
    STEPG(0, C0, C1, C2, C3, 4, Bp, 2);                                        \
    STEPG(1, C0, C1, C2, C3, 5, Bp, 3);                                        \
    STEPG(0, C0, C1, C2, C3, 6, Bp, 4);                                        \
    STEPG(1, C0, C1, C2, C3, 7, Bp, 5);                                        \
    STEPG(0, N0, N1, N2, N3, 0, Bp, 6);                                        \
    STEPG(1, N0, N1, N2, N3, 1, Bp, 7);                                        \
} while (0)

// Fill group0 with kt0, group1 with kt1 (parts 0..2, 4 tiles)
#define PREFILL4(T0, T1, T2, T3) do {                                          \
    q00a = (T0)[0 * 1024]; q00b = (T0)[8 * 1024]; q00c = (T0)[16 * 1024];      \
    q01a = (T1)[0 * 1024]; q01b = (T1)[8 * 1024]; q01c = (T1)[16 * 1024];      \
    q02a = (T2)[0 * 1024]; q02b = (T2)[8 * 1024]; q02c = (T2)[16 * 1024];      \
    q03a = (T3)[0 * 1024]; q03b = (T3)[8 * 1024]; q03c = (T3)[16 * 1024];      \
    q10a = (T0)[1 * 1024]; q10b = (T0)[9 * 1024]; q10c = (T0)[17 * 1024];      \
    q11a = (T1)[1 * 1024]; q11b = (T1)[9 * 1024]; q11c = (T1)[17 * 1024];      \
    q12a = (T2)[1 * 1024]; q12b = (T2)[9 * 1024]; q12c = (T2)[17 * 1024];      \
    q13a = (T3)[1 * 1024]; q13b = (T3)[9 * 1024]; q13c = (T3)[17 * 1024];      \
} while (0)

// li_out walker for timestep t (wave 0 only). Ascending-k fmaf chain over
// S3F spikes (0.0/1.0): fmaf(1,w,p)=round(p+w), fmaf(0,w,p)=p -> bit-identical
// to the baseline select-add chain ("skip-zero == exact chain").
__device__ __forceinline__ void li_walker(
    const float* __restrict__ WoutS, const float (*__restrict__ S3F)[260],
    int wb, int ooc, float bto, float bo, float& m3s,
    float* __restrict__ rec, int t, int b0, int lane)
{
    if (lane < 32) {
        const float* wrow = WoutS + ooc * HH;
        const float* srow = S3F[wb];
        float p = 0.f;
#pragma unroll 8
        for (int k4 = 0; k4 < 64; ++k4) {
            float4 sv = *(const float4*)(srow + k4 * 4);
            float4 wv = *(const float4*)(wrow + k4 * 4);
            p = fmaf(sv.x, wv.x, p);
            p = fmaf(sv.y, wv.y, p);
            p = fmaf(sv.z, wv.z, p);
            p = fmaf(sv.w, wv.w, p);
        }
        float mm3 = fmaf(bto, m3s, p);
        mm3 = mm3 + bo;
        m3s = mm3;
        float spk = ((m3s - 1.0f) > 0.f) ? 1.f : 0.f;
        float om3 = __shfl_xor(m3s, 16, 64);
        float osp = __shfl_xor(spk, 16, 64);
        if (lane < 16) {
            *(float4*)(rec + ((size_t)t * BB + b0 + wb) * 4) =
                make_float4(spk, osp, m3s, om3);
        }
    }
}

__global__ __launch_bounds__(256) void snn_main_kernel(
    const float* __restrict__ x,
    const float* __restrict__ W_in, const float* __restrict__ b_in,
    const float* __restrict__ beta_in, const float* __restrict__ thr_in,
    const float* __restrict__ b_h, const float* __restrict__ beta_h, const float* __restrict__ thr_h,
    const float* __restrict__ b_h2, const float* __restrict__ beta_h2, const float* __restrict__ thr_h2,
    const float* __restrict__ W_out, const float* __restrict__ b_out, const float* __restrict__ beta_out,
    const unsigned short* __restrict__ WA, const float* __restrict__ emb,
    float* __restrict__ rec)
{
#pragma clang fp contract(off)   // all contraction EXPLICIT via fmaf
    const int tid = threadIdx.x;
    const int w = tid >> 6;       // wave 0..3: owns n-tiles 4w..4w+3
    const int lane = tid & 63;
    const int b = lane & 15;      // batch column (D col = lane&15)
    const int g = lane >> 4;      // row group   (D row = g*4+reg)
    const int b0 = blockIdx.x * BMb;

    // static LDS kept at 61952 B ON PURPOSE: floor(160KB/62KB)=2 blocks ->
    // 8 waves/CU -> 2 waves/EU -> VGPR budget 256 (the regalloc lever).
    __shared__ unsigned short sbuf1[8 * 64 * 8];            // B-frags spikes layer1 (8 KB)
    __shared__ unsigned short sbuf2[8 * 64 * 8];            // B-frags spikes layer2 (8 KB)
    __shared__ __align__(16) float S3F[16][260];            // layer-3 spikes [batch][n]
    __shared__ __align__(16) float WoutS[2 * HH];
    __shared__ float4 PL1a[HH];   // {wi0, wi1, wi2, b_in}
    __shared__ float2 PL1b[HH];   // {bt1c, th1}
    __shared__ float4 PL2[HH];    // {b_h,  bt2c, th2, -}
    __shared__ float4 PL3[HH];    // {b_h2, bt3c, th3, -}
    __shared__ float  xs[TT][BMb][3];   // staged x slice (12 KB)
    __shared__ float  embS[TT];

#pragma unroll
    for (int i = tid; i < 2 * HH; i += 256) WoutS[i] = W_out[i];
    {
        int n = tid;
        PL1a[n] = make_float4(W_in[n * 3], W_in[n * 3 + 1], W_in[n * 3 + 2], b_in[n]);
        PL1b[n] = make_float2(clip01f(beta_in[n]), thr_in[n]);
        PL2[n]  = make_float4(b_h[n],  clip01f(beta_h[n]),  thr_h[n],  0.f);
        PL3[n]  = make_float4(b_h2[n], clip01f(beta_h2[n]), thr_h2[n], 0.f);
    }
    if (tid < TT) embS[tid] = emb[tid];
#pragma unroll
    for (int i = tid; i < TT * BMb; i += 256) {   // 4 iters: 64 t * 16 batches
        int ts = i >> 4, bb = i & 15;
        const float* xp = x + ((size_t)ts * BB + b0 + bb) * 3;
        xs[ts][bb][0] = xp[0];
        xs[ts][bb][1] = xp[1];
        xs[ts][bb][2] = xp[2];
    }

    // this thread's 16 neurons: n = nb0 + u*16 + r, u in 0..3 (tile 4w+u)
    const int nb0 = w * 64 + g * 4;

    float m1[4][4], m2[4][4], m4[4][4];
#pragma unroll
    for (int u = 0; u < 4; ++u)
#pragma unroll
        for (int r = 0; r < 4; ++r) { m1[u][r] = 0.f; m2[u][r] = 0.f; m4[u][r] = 0.f; }

    // spike -> B-frag LDS address for tile nt=4w+u (one b64 per thread per tile):
    // k=n: kt2 = nt>>1, q = (nt&1)*2 + (g>>1), dst_lane = q*16+b, j0 = (g&1)*4
    // off(u) = base + u&1 ? +256 : 0, +512 per u>>1
    const int sbB = ((2 * w) * 64 + ((g >> 1) * 16 + b)) * 8 + (g & 1) * 4;

    // li_out walker state (wave 0, lanes 0..31): wb = batch, ooc = channel
    const int wb = lane & 15;
    const int ooc = (lane >> 4) & 1;
    float bto = clip01f(beta_out[ooc]);
    float bo = b_out[ooc];
    float m3s = 0.f;

    // A-fragment bases, pre-offset by (tile, lane); uint4 units. layer stride 24576.
    const uint4* WAu4 = (const uint4*)WA;
    const uint4* P20 = WAu4 + (size_t)(4 * w) * 64 + lane;   // layer2 tiles
    const uint4* P21 = P20 + 64;
    const uint4* P22 = P20 + 128;
    const uint4* P23 = P20 + 192;
    const uint4* P30 = P20 + 24576;                          // layer3 tiles
    const uint4* P31 = P21 + 24576;
    const uint4* P32 = P22 + 24576;
    const uint4* P33 = P23 + 24576;
    const uint4* Bp1 = (const uint4*)sbuf1 + lane;
    const uint4* Bp2 = (const uint4*)sbuf2 + lane;

    // 24 NAMED prefetch slots (96 VGPRs): group q0* = even kt, q1* = odd kt;
    // each group = 4 tiles x parts {a,b,c}. Depth-2 ring over kt.
    uint4 q00a, q00b, q00c, q01a, q01b, q01c, q02a, q02b, q02c, q03a, q03b, q03c;
    uint4 q10a, q10b, q10c, q11a, q11b, q11c, q12a, q12b, q12c, q13a, q13b, q13c;
    PREFILL4(P20, P21, P22, P23);   // t=0 layer-2 kt0,kt1 in flight before the loop

    __syncthreads();              // LDS init visible; prefill drains free here

    for (int t = 0; t < TT; ++t) {
        // ---- phase A: layer 1 (16 neurons/thread), exact f32 chain + contracted LIF ----
        {
            float et = embS[t];
            float xe0 = xs[t][b][0] * et;
            float xe1 = xs[t][b][1] * et;
            float xe2 = xs[t][b][2] * et;
            unsigned sp[4][4];
#pragma unroll
            for (int u = 0; u < 4; ++u)
#pragma unroll
            for (int r = 0; r < 4; ++r) {
                int n = nb0 + u * 16 + r;
                float4 pa = PL1a[n];
                float2 pb = PL1b[n];
                float a1 = xe0 * pa.x;
                a1 = fmaf(xe1, pa.y, a1);
                a1 = fmaf(xe2, pa.z, a1);
                float cur = a1 + pa.w;
                float rf = ((m1[u][r] - pb.y) > 0.f) ? 1.f : 0.f;  // reset from PREVIOUS mem
                float mm = fmaf(pb.x, m1[u][r], cur);              // contracted: beta*m + cur
                mm = fmaf(-rf, pb.y, mm);                          // contracted: - reset*thr
                m1[u][r] = mm;
                sp[u][r] = ((mm - pb.y) > 0.f) ? 0x3F80u : 0u;     // bf16 1.0 / 0.0
            }
            *(uint2*)(sbuf1 + sbB)       = make_uint2(sp[0][0] | (sp[0][1] << 16), sp[0][2] | (sp[0][3] << 16));
            *(uint2*)(sbuf1 + sbB + 256) = make_uint2(sp[1][0] | (sp[1][1] << 16), sp[1][2] | (sp[1][3] << 16));
            *(uint2*)(sbuf1 + sbB + 512) = make_uint2(sp[2][0] | (sp[2][1] << 16), sp[2][2] | (sp[2][3] << 16));
            *(uint2*)(sbuf1 + sbB + 768) = make_uint2(sp[3][0] | (sp[3][1] << 16), sp[3][2] | (sp[3][3] << 16));
        }
        __syncthreads();   // BAR1

        // ---- phase B: wave0 runs walker(t-1) first (other waves proceed);
        //      layer-2 MFMA (4 tiles) with named-reg prefetched A; epilogue LIF ----
        if (w == 0 && t > 0)
            li_walker(WoutS, S3F, wb, ooc, bto, bo, m3s, rec, t - 1, b0, lane);
        {
            f32x4_t D0 = (f32x4_t){0.f, 0.f, 0.f, 0.f};
            f32x4_t D1 = (f32x4_t){0.f, 0.f, 0.f, 0.f};
            f32x4_t D2 = (f32x4_t){0.f, 0.f, 0.f, 0.f};
            f32x4_t D3 = (f32x4_t){0.f, 0.f, 0.f, 0.f};
            MFMA_PHASE4(P20, P21, P22, P23, P30, P31, P32, P33, Bp1);
            unsigned sp[4][4];
#pragma unroll
            for (int u = 0; u < 4; ++u) {
                f32x4_t Du = (u == 0) ? D0 : (u == 1) ? D1 : (u == 2) ? D2 : D3;
#pragma unroll
                for (int r = 0; r < 4; ++r) {
                    int n = nb0 + u * 16 + r;
                    float4 p2 = PL2[n];
                    float cur = Du[r] + p2.x;
                    float rf = ((m2[u][r] - p2.z) > 0.f) ? 1.f : 0.f;
                    float mm = fmaf(p2.y, m2[u][r], cur);
                    mm = fmaf(-rf, p2.z, mm);
                    m2[u][r] = mm;
                    sp[u][r] = ((mm - p2.z) > 0.f) ? 0x3F80u : 0u;
                }
            }
            *(uint2*)(sbuf2 + sbB)       = make_uint2(sp[0][0] | (sp[0][1] << 16), sp[0][2] | (sp[0][3] << 16));
            *(uint2*)(sbuf2 + sbB + 256) = make_uint2(sp[1][0] | (sp[1][1] << 16), sp[1][2] | (sp[1][3] << 16));
            *(uint2*)(sbuf2 + sbB + 512) = make_uint2(sp[2][0] | (sp[2][1] << 16), sp[2][2] | (sp[2][3] << 16));
            *(uint2*)(sbuf2 + sbB + 768) = make_uint2(sp[3][0] | (sp[3][1] << 16), sp[3][2] | (sp[3][3] << 16));
        }
        __syncthreads();   // BAR2 (also fences walker's S3F reads vs next writes)

        // ---- phase C: layer-3 MFMA (4 tiles); epilogue LIF -> S3F spike floats ----
        {
            f32x4_t D0 = (f32x4_t){0.f, 0.f, 0.f, 0.f};
            f32x4_t D1 = (f32x4_t){0.f, 0.f, 0.f, 0.f};
            f32x4_t D2 = (f32x4_t){0.f, 0.f, 0.f, 0.f};
            f32x4_t D3 = (f32x4_t){0.f, 0.f, 0.f, 0.f};
            MFMA_PHASE4(P30, P31, P32, P33, P20, P21, P22, P23, Bp2);
#pragma unroll
            for (int u = 0; u < 4; ++u) {
                f32x4_t Du = (u == 0) ? D0 : (u == 1) ? D1 : (u == 2) ? D2 : D3;
                float s3v[4];
#pragma unroll
                for (int r = 0; r < 4; ++r) {
                    int n = nb0 + u * 16 + r;
                    float4 p3 = PL3[n];
                    float cur = Du[r] + p3.x;
                    float rf = ((m4[u][r] - p3.z) > 0.f) ? 1.f : 0.f;
                    float mm = fmaf(p3.y, m4[u][r], cur);
                    mm = fmaf(-rf, p3.z, mm);
                    m4[u][r] = mm;
                    s3v[r] = ((mm - p3.z) > 0.f) ? 1.0f : 0.0f;
                }
                *(float4*)(&S3F[b][nb0 + u * 16]) = make_float4(s3v[0], s3v[1], s3v[2], s3v[3]);
            }
        }
        __syncthreads();   // BAR3
    }

    // final walker for t = 63
    if (w == 0)
        li_walker(WoutS, S3F, wb, ooc, bto, bo, m3s, rec, TT - 1, b0, lane);
}

// out[r,o] = (ascending-k fma dot) + b_pred[o]
__global__ __launch_bounds__(256) void pred_kernel(
    const float* __restrict__ rec, const float* __restrict__ W_pred,
    const float* __restrict__ b_pred, float* __restrict__ out)
{
#pragma clang fp contract(off)
    int r = blockIdx.x * 256 + threadIdx.x;   // 0..4095
    const float* f = rec + (size_t)r * 256;
    float a0 = 0.f, a1 = 0.f;
#pragma unroll 4
    for (int c = 0; c < 256; ++c) {
        float v = f[c];
        a0 = fmaf(v, W_pred[c], a0);
        a1 = fmaf(v, W_pred[256 + c], a1);
    }
    out[r * 2 + 0] = a0 + b_pred[0];
    out[r * 2 + 1] = a1 + b_pred[1];
}

extern "C" void kernel_launch(void* const* d_in, const int* in_sizes, int n_in,
                              void* d_out, int out_size, void* d_ws, size_t ws_size,
                              hipStream_t stream)
{
    const float* x        = (const float*)d_in[0];
    const float* W_in     = (const float*)d_in[1];
    const float* b_in     = (const float*)d_in[2];
    const float* beta_in  = (const float*)d_in[3];
    const float* thr_in   = (const float*)d_in[4];
    const float* W_h      = (const float*)d_in[5];
    const float* b_h      = (const float*)d_in[6];
    const float* beta_h   = (const float*)d_in[7];
    const float* thr_h    = (const float*)d_in[8];
    const float* W_h2     = (const float*)d_in[9];
    const float* b_h2     = (const float*)d_in[10];
    const float* beta_h2  = (const float*)d_in[11];
    const float* thr_h2   = (const float*)d_in[12];
    const float* W_out    = (const float*)d_in[13];
    const float* b_out    = (const float*)d_in[14];
    const float* beta_out = (const float*)d_in[15];
    const float* W_pred   = (const float*)d_in[16];
    const float* b_pred   = (const float*)d_in[17];

    char* ws = (char*)d_ws;
    unsigned short* WA = (unsigned short*)(ws + WS_WA_B);
    float* emb = (float*)(ws + WS_EMB_B);
    float* rec = (float*)(ws + WS_REC_B);

    split_weights_kernel<<<1536, 256, 0, stream>>>(W_h, W_h2, WA);
    setup_emb_kernel<<<1, 64, 0, stream>>>(emb);

    snn_main_kernel<<<NBLK, 256, 0, stream>>>(
        x, W_in, b_in, beta_in, thr_in,
        b_h, beta_h, thr_h,
        b_h2, beta_h2, thr_h2,
        W_out, b_out, beta_out,
        WA, emb, rec);

    pred_kernel<<<BB / 256, 256, 0, stream>>>(rec, W_pred, b_pred, (float*)d_out);
}

// Round 6
// 1698.174 us; speedup vs baseline: 1.5256x; 1.5256x over previous
//
#include <hip/hip_runtime.h>
#include <hip/hip_bf16.h>

#define TT 64
#define BB 4096
#define HH 256
#define BMb 16             // batches per block
#define NBLK (BB / BMb)    // 256 blocks -> 1 block/CU, 8 waves (2/SIMD)

typedef short bf16x8_t __attribute__((ext_vector_type(8)));
typedef float f32x4_t  __attribute__((ext_vector_type(4)));

// d_ws layout (byte offsets)
#define WS_WA_B   0u          // split bf16 weights: 2 layers*3 parts*8kt*16nt*64lane*8j shorts = 768 KB
#define WS_EMB_B  786432u     // emb f32
#define WS_REC_B  1048576u    // rec f32 [T][B][4], 4 MB

__device__ __forceinline__ float clip01f(float v) {
    return fminf(fmaxf(v, 0.0f), 1.0f);
}

__global__ __launch_bounds__(64) void setup_emb_kernel(float* __restrict__ emb) {
    int i = threadIdx.x;
    const double sigma = 64.0 / 10.0;
    const double c = 32.0;
    double d = ((double)i - c) / sigma;
    double e = exp(-0.5 * (d * d));
    double d0 = (0.0 - c) / sigma;
    double emin = exp(-0.5 * (d0 * d0));
    emb[i] = (float)((e - emin) / (1.0 - emin));
}

// Exact 3-way split w = hi + mid + lo into bf16 parts (residuals exact).
// Pre-swizzled to A-fragment order for mfma_f32_16x16x32_bf16:
// A[m=lane&15][k=(lane>>4)*8+j], flat = ((((layer*3+part)*8+kt)*16+ntile)*64+lane)*8+j
__global__ __launch_bounds__(256) void split_weights_kernel(
    const float* __restrict__ W_h, const float* __restrict__ W_h2,
    unsigned short* __restrict__ WA)
{
    int flat = blockIdx.x * 256 + threadIdx.x;     // < 393216
    int j     = flat & 7;
    int lane  = (flat >> 3) & 63;
    int ntile = (flat >> 9) & 15;
    int kt    = (flat >> 13) & 7;
    int rest  = flat >> 16;                        // 0..5
    int part  = rest % 3;
    int layer = rest / 3;
    int k = kt * 32 + (lane >> 4) * 8 + j;
    int n = ntile * 16 + (lane & 15);
    const float* W = layer ? W_h2 : W_h;           // row-major [n][k] = W[n*256+k]
    float w = W[n * HH + k];
    __hip_bfloat16 h = __float2bfloat16(w);
    float r1 = w - __bfloat162float(h);
    __hip_bfloat16 m = __float2bfloat16(r1);
    float r2 = r1 - __bfloat162float(m);
    __hip_bfloat16 l = __float2bfloat16(r2);
    __hip_bfloat16 v = (part == 0) ? h : ((part == 1) ? m : l);
    WA[flat] = *reinterpret_cast<unsigned short*>(&v);
}

union U16x8 { uint4 u; bf16x8_t v; };

// ---- 512-thread / 8-wave structure: wave w owns n-tiles {2w, 2w+1}. ----
// Regalloc model (R1-R5, validated): compile-time VGPR budget = 512 / (waves/EU
// implied by STATIC LDS occupancy). 62KB static -> 2 blocks/CU -> 4 waves/EU at
// 512 thr -> budget 128 -> the 12-slot prefetch spilled (R4: WRITE 135MB, L2
// thrash). Fix: pad static LDS past 80KB -> compiler plans 1 block/CU -> 2
// waves/EU -> budget 256. Runtime cost ZERO: grid=256 means exactly 1 block/CU
// regardless. Step order is MFMA-from-slots THEN refill (no copies -> live set
// ~150 regs: 12 slots=48 + D=8 + m=24 + addr/misc).
//
// STEP2: consume slot-group via 6 MFMAs (both tiles, parts 0,1,2 in order ->
// per-D accumulation order IDENTICAL to baseline -> bit-identical D), then
// refill the group with kt+2 (or the next phase's kt0/kt1 at steps 6/7).
#define STEP2(A0, A1, A2, B0, B1, B2, Wr0, Wr1, ktr, Bp, ktb, D0, D1) do {     \
    U16x8 br_; br_.u = (Bp)[(ktb) * 64];            /* ds_read_b128 spikes */  \
    U16x8 x0_, x1_, x2_, y0_, y1_, y2_;             /* bitcasts, fold to 0 movs */ \
    x0_.u = A0; x1_.u = A1; x2_.u = A2;                                        \
    y0_.u = B0; y1_.u = B1; y2_.u = B2;                                        \
    D0 = __builtin_amdgcn_mfma_f32_16x16x32_bf16(x0_.v, br_.v, D0, 0, 0, 0);   \
    D0 = __builtin_amdgcn_mfma_f32_16x16x32_bf16(x1_.v, br_.v, D0, 0, 0, 0);   \
    D0 = __builtin_amdgcn_mfma_f32_16x16x32_bf16(x2_.v, br_.v, D0, 0, 0, 0);   \
    D1 = __builtin_amdgcn_mfma_f32_16x16x32_bf16(y0_.v, br_.v, D1, 0, 0, 0);   \
    D1 = __builtin_amdgcn_mfma_f32_16x16x32_bf16(y1_.v, br_.v, D1, 0, 0, 0);   \
    D1 = __builtin_amdgcn_mfma_f32_16x16x32_bf16(y2_.v, br_.v, D1, 0, 0, 0);   \
    A0 = (Wr0)[(0 * 8 + (ktr)) * 1024];                                        \
    A1 = (Wr0)[(1 * 8 + (ktr)) * 1024];                                        \
    A2 = (Wr0)[(2 * 8 + (ktr)) * 1024];                                        \
    B0 = (Wr1)[(0 * 8 + (ktr)) * 1024];                                        \
    B1 = (Wr1)[(1 * 8 + (ktr)) * 1024];                                        \
    B2 = (Wr1)[(2 * 8 + (ktr)) * 1024];                                        \
} while (0)

// kt = 0..7 ascending; enters with g0=kt0, g1=kt1 (issued >=2 steps earlier);
// steps 0..5 refill kt+2, steps 6..7 refill NEXT phase's kt0/kt1.
#define MFMA_PHASE2(Wc0, Wc1, Wn0, Wn1, Bp, D0, D1) do {                       \
    STEP2(g0t0a, g0t0b, g0t0c, g0t1a, g0t1b, g0t1c, Wc0, Wc1, 2, Bp, 0, D0, D1); \
    STEP2(g1t0a, g1t0b, g1t0c, g1t1a, g1t1b, g1t1c, Wc0, Wc1, 3, Bp, 1, D0, D1); \
    STEP2(g0t0a, g0t0b, g0t0c, g0t1a, g0t1b, g0t1c, Wc0, Wc1, 4, Bp, 2, D0, D1); \
    STEP2(g1t0a, g1t0b, g1t0c, g1t1a, g1t1b, g1t1c, Wc0, Wc1, 5, Bp, 3, D0, D1); \
    STEP2(g0t0a, g0t0b, g0t0c, g0t1a, g0t1b, g0t1c, Wc0, Wc1, 6, Bp, 4, D0, D1); \
    STEP2(g1t0a, g1t0b, g1t0c, g1t1a, g1t1b, g1t1c, Wc0, Wc1, 7, Bp, 5, D0, D1); \
    STEP2(g0t0a, g0t0b, g0t0c, g0t1a, g0t1b, g0t1c, Wn0, Wn1, 0, Bp, 6, D0, D1); \
    STEP2(g1t0a, g1t0b, g1t0c, g1t1a, g1t1b, g1t1c, Wn0, Wn1, 1, Bp, 7, D0, D1); \
} while (0)

// Fill g0 with kt0, g1 with kt1 (parts 0..2, both tiles): slot = W[(part*8+kt)*1024]
#define PREFILL2(Wt0, Wt1) do {                                                \
    g0t0a = (Wt0)[ 0 * 1024]; g0t0b = (Wt0)[ 8 * 1024]; g0t0c = (Wt0)[16 * 1024]; \
    g0t1a = (Wt1)[ 0 * 1024]; g0t1b = (Wt1)[ 8 * 1024]; g0t1c = (Wt1)[16 * 1024]; \
    g1t0a = (Wt0)[ 1 * 1024]; g1t0b = (Wt0)[ 9 * 1024]; g1t0c = (Wt0)[17 * 1024]; \
    g1t1a = (Wt1)[ 1 * 1024]; g1t1b = (Wt1)[ 9 * 1024]; g1t1c = (Wt1)[17 * 1024]; \
} while (0)

// li_out walker for timestep t (wave 0 only). Ascending-k fmaf chain over
// S3F spikes (0.0/1.0): fmaf(1,w,p)=round(p+w), fmaf(0,w,p)=p -> bit-identical
// to the baseline select-add chain ("skip-zero == exact chain").
__device__ __forceinline__ void li_walker(
    const float* __restrict__ WoutS, const float (*__restrict__ S3F)[260],
    int wb, int ooc, float bto, float bo, float& m3s,
    float* __restrict__ rec, int t, int b0, int lane)
{
    if (lane < 32) {
        const float* wrow = WoutS + ooc * HH;
        const float* srow = S3F[wb];
        float p = 0.f;
#pragma unroll 8
        for (int k4 = 0; k4 < 64; ++k4) {
            float4 sv = *(const float4*)(srow + k4 * 4);
            float4 wv = *(const float4*)(wrow + k4 * 4);
            p = fmaf(sv.x, wv.x, p);
            p = fmaf(sv.y, wv.y, p);
            p = fmaf(sv.z, wv.z, p);
            p = fmaf(sv.w, wv.w, p);
        }
        float mm3 = fmaf(bto, m3s, p);
        mm3 = mm3 + bo;
        m3s = mm3;
        float spk = ((m3s - 1.0f) > 0.f) ? 1.f : 0.f;
        float om3 = __shfl_xor(m3s, 16, 64);
        float osp = __shfl_xor(spk, 16, 64);
        if (lane < 16) {
            *(float4*)(rec + ((size_t)t * BB + b0 + wb) * 4) =
                make_float4(spk, osp, m3s, om3);
        }
    }
}

__global__ __launch_bounds__(512) void snn_main_kernel(
    const float* __restrict__ x,
    const float* __restrict__ W_in, const float* __restrict__ b_in,
    const float* __restrict__ beta_in, const float* __restrict__ thr_in,
    const float* __restrict__ b_h, const float* __restrict__ beta_h, const float* __restrict__ thr_h,
    const float* __restrict__ b_h2, const float* __restrict__ beta_h2, const float* __restrict__ thr_h2,
    const float* __restrict__ W_out, const float* __restrict__ b_out, const float* __restrict__ beta_out,
    const unsigned short* __restrict__ WA, const float* __restrict__ emb,
    float* __restrict__ rec)
{
#pragma clang fp contract(off)   // all contraction EXPLICIT via fmaf
    const int tid = threadIdx.x;
    const int w = tid >> 6;       // wave 0..7: owns n-tiles 2w, 2w+1
    const int lane = tid & 63;
    const int b = lane & 15;      // batch column (D col = lane&15)
    const int g = lane >> 4;      // row group   (D row = g*4+reg)
    const int b0 = blockIdx.x * BMb;

    __shared__ unsigned short sbuf1[8 * 64 * 8];            // B-frags spikes layer1 (8 KB)
    __shared__ unsigned short sbuf2[8 * 64 * 8];            // B-frags spikes layer2 (8 KB)
    __shared__ __align__(16) float S3F[16][260];            // layer-3 spikes [batch][n]
    __shared__ __align__(16) float WoutS[2 * HH];
    __shared__ float4 PL1a[HH];   // {wi0, wi1, wi2, b_in}
    __shared__ float2 PL1b[HH];   // {bt1c, th1}
    __shared__ float4 PL2[HH];    // {b_h,  bt2c, th2, -}
    __shared__ float4 PL3[HH];    // {b_h2, bt3c, th3, -}
    __shared__ float  xs[TT][BMb][3];   // staged x slice (12 KB)
    __shared__ float  embS[TT];
    // Occupancy/regalloc lever (R1-R5 model): pad static LDS to 82432 B so the
    // compiler plans 1 block/CU -> 8 waves/CU -> 2 waves/EU -> VGPR budget 256.
    // Runtime-free: grid=256 blocks = 1 block/CU regardless of this pad.
    __shared__ char lds_pad[20480];
    if (tid == 0) *(volatile char*)lds_pad = 0;   // keep the pad allocated

    WoutS[tid] = W_out[tid];      // 512 threads = 512 elems
    if (tid < HH) {
        int n = tid;
        PL1a[n] = make_float4(W_in[n * 3], W_in[n * 3 + 1], W_in[n * 3 + 2], b_in[n]);
        PL1b[n] = make_float2(clip01f(beta_in[n]), thr_in[n]);
        PL2[n]  = make_float4(b_h[n],  clip01f(beta_h[n]),  thr_h[n],  0.f);
        PL3[n]  = make_float4(b_h2[n], clip01f(beta_h2[n]), thr_h2[n], 0.f);
    }
    if (tid < TT) embS[tid] = emb[tid];
#pragma unroll
    for (int i = tid; i < TT * BMb; i += 512) {   // 2 iters: 64 t * 16 batches
        int ts = i >> 4, bb = i & 15;
        const float* xp = x + ((size_t)ts * BB + b0 + bb) * 3;
        xs[ts][bb][0] = xp[0];
        xs[ts][bb][1] = xp[1];
        xs[ts][bb][2] = xp[2];
    }

    // this thread's 8 neurons: n = (2w+u)*16 + g*4 + r, u in {0,1}
    const int nb0 = w * 32 + g * 4;

    float m1[2][4], m2[2][4], m4[2][4];
#pragma unroll
    for (int u = 0; u < 2; ++u)
#pragma unroll
        for (int r = 0; r < 4; ++r) { m1[u][r] = 0.f; m2[u][r] = 0.f; m4[u][r] = 0.f; }

    // spike -> B-frag LDS address for tile nt=2w+u (one b64 per thread per tile):
    // k=n: kt2 = nt>>1 = w, q = (nt&1)*2 + (g>>1), dst_lane = q*16+b, j0 = (g&1)*4
    // u=0 at sb0, u=1 at sb0+256 (q += 2 -> +32 lanes * 8 shorts)
    const int sb0 = ((w * 64 + ((g >> 1) * 16 + b)) * 8 + (g & 1) * 4);

    // li_out walker state (wave 0, lanes 0..31): wb = batch, ooc = channel
    const int wb = lane & 15;
    const int ooc = (lane >> 4) & 1;
    float bto = clip01f(beta_out[ooc]);
    float bo = b_out[ooc];
    float m3s = 0.f;

    // A-fragment bases, pre-offset by this thread's (tile, lane); uint4 units.
    // flat idx = ((layer*3+part)*8+kt)*16 + ntile)*64 + lane; layer stride = 24576.
    const uint4* W00 = (const uint4*)WA + (size_t)(2 * w) * 64 + lane;  // layer2 tile0
    const uint4* W01 = W00 + 64;                                        // layer2 tile1
    const uint4* W10 = W00 + 24576;                                     // layer3 tile0
    const uint4* W11 = W01 + 24576;                                     // layer3 tile1
    const uint4* Bp1 = (const uint4*)sbuf1 + lane;
    const uint4* Bp2 = (const uint4*)sbuf2 + lane;

    // 12 NAMED prefetch slots (48 VGPRs): groups g0 (even kt), g1 (odd kt),
    // each = {tile0, tile1} x {part0,1,2}. Depth-2 ring over kt.
    uint4 g0t0a, g0t0b, g0t0c, g0t1a, g0t1b, g0t1c;
    uint4 g1t0a, g1t0b, g1t0c, g1t1a, g1t1b, g1t1c;
    PREFILL2(W00, W01);           // t=0 layer-2 kt0,kt1 in flight before the loop

    __syncthreads();              // LDS init visible; prefill drains free here

    for (int t = 0; t < TT; ++t) {
        // ---- phase A: layer 1, exact f32 chain + contracted LIF; spikes -> B-frag LDS ----
        {
            float et = embS[t];
            float xe0 = xs[t][b][0] * et;
            float xe1 = xs[t][b][1] * et;
            float xe2 = xs[t][b][2] * et;
            unsigned sp[2][4];
#pragma unroll
            for (int u = 0; u < 2; ++u)
#pragma unroll
            for (int r = 0; r < 4; ++r) {
                int n = nb0 + u * 16 + r;
                float4 pa = PL1a[n];
                float2 pb = PL1b[n];
                float a1 = xe0 * pa.x;
                a1 = fmaf(xe1, pa.y, a1);
                a1 = fmaf(xe2, pa.z, a1);
                float cur = a1 + pa.w;
                float rf = ((m1[u][r] - pb.y) > 0.f) ? 1.f : 0.f;  // reset from PREVIOUS mem
                float mm = fmaf(pb.x, m1[u][r], cur);              // contracted: beta*m + cur
                mm = fmaf(-rf, pb.y, mm);                          // contracted: - reset*thr
                m1[u][r] = mm;
                sp[u][r] = ((mm - pb.y) > 0.f) ? 0x3F80u : 0u;     // bf16 1.0 / 0.0
            }
            *(uint2*)(sbuf1 + sb0)       = make_uint2(sp[0][0] | (sp[0][1] << 16), sp[0][2] | (sp[0][3] << 16));
            *(uint2*)(sbuf1 + sb0 + 256) = make_uint2(sp[1][0] | (sp[1][1] << 16), sp[1][2] | (sp[1][3] << 16));
        }
        __syncthreads();   // BAR1

        // ---- phase B: wave0 runs walker(t-1) first (hides under others' MFMA/VMEM);
        //      then layer-2 MFMA (2 tiles) with named-reg prefetched A; epilogue LIF ----
        if (w == 0 && t > 0)
            li_walker(WoutS, S3F, wb, ooc, bto, bo, m3s, rec, t - 1, b0, lane);
        {
            f32x4_t D0 = (f32x4_t){0.f, 0.f, 0.f, 0.f};
            f32x4_t D1 = (f32x4_t){0.f, 0.f, 0.f, 0.f};
            MFMA_PHASE2(W00, W01, W10, W11, Bp1, D0, D1);  // exits with slots = layer-3 kt0,kt1
            unsigned sp[2][4];
#pragma unroll
            for (int r = 0; r < 4; ++r) {
                int n0 = nb0 + r;
                float4 p2 = PL2[n0];
                float cur = D0[r] + p2.x;
                float rf = ((m2[0][r] - p2.z) > 0.f) ? 1.f : 0.f;
                float mm = fmaf(p2.y, m2[0][r], cur);
                mm = fmaf(-rf, p2.z, mm);
                m2[0][r] = mm;
                sp[0][r] = ((mm - p2.z) > 0.f) ? 0x3F80u : 0u;
            }
#pragma unroll
            for (int r = 0; r < 4; ++r) {
                int n1 = nb0 + 16 + r;
                float4 p2 = PL2[n1];
                float cur = D1[r] + p2.x;
                float rf = ((m2[1][r] - p2.z) > 0.f) ? 1.f : 0.f;
                float mm = fmaf(p2.y, m2[1][r], cur);
                mm = fmaf(-rf, p2.z, mm);
                m2[1][r] = mm;
                sp[1][r] = ((mm - p2.z) > 0.f) ? 0x3F80u : 0u;
            }
            *(uint2*)(sbuf2 + sb0)       = make_uint2(sp[0][0] | (sp[0][1] << 16), sp[0][2] | (sp[0][3] << 16));
            *(uint2*)(sbuf2 + sb0 + 256) = make_uint2(sp[1][0] | (sp[1][1] << 16), sp[1][2] | (sp[1][3] << 16));
        }
        __syncthreads();   // BAR2 (also fences walker's S3F reads vs next writes)

        // ---- phase C: layer-3 MFMA (2 tiles); epilogue LIF -> S3F spike floats ----
        {
            f32x4_t E0 = (f32x4_t){0.f, 0.f, 0.f, 0.f};
            f32x4_t E1 = (f32x4_t){0.f, 0.f, 0.f, 0.f};
            MFMA_PHASE2(W10, W11, W00, W01, Bp2, E0, E1);  // exits with slots = next-t layer-2 kt0,kt1
            float s3v[2][4];
#pragma unroll
            for (int r = 0; r < 4; ++r) {
                int n0 = nb0 + r;
                float4 p3 = PL3[n0];
                float cur = E0[r] + p3.x;
                float rf = ((m4[0][r] - p3.z) > 0.f) ? 1.f : 0.f;
                float mm = fmaf(p3.y, m4[0][r], cur);
                mm = fmaf(-rf, p3.z, mm);
                m4[0][r] = mm;
                s3v[0][r] = ((mm - p3.z) > 0.f) ? 1.0f : 0.0f;
            }
#pragma unroll
            for (int r = 0; r < 4; ++r) {
                int n1 = nb0 + 16 + r;
                float4 p3 = PL3[n1];
                float cur = E1[r] + p3.x;
                float rf = ((m4[1][r] - p3.z) > 0.f) ? 1.f : 0.f;
                float mm = fmaf(p3.y, m4[1][r], cur);
                mm = fmaf(-rf, p3.z, mm);
                m4[1][r] = mm;
                s3v[1][r] = ((mm - p3.z) > 0.f) ? 1.0f : 0.0f;
            }
            *(float4*)(&S3F[b][nb0])      = make_float4(s3v[0][0], s3v[0][1], s3v[0][2], s3v[0][3]);
            *(float4*)(&S3F[b][nb0 + 16]) = make_float4(s3v[1][0], s3v[1][1], s3v[1][2], s3v[1][3]);
        }
        __syncthreads();   // BAR3
    }

    // final walker for t = 63
    if (w == 0)
        li_walker(WoutS, S3F, wb, ooc, bto, bo, m3s, rec, TT - 1, b0, lane);
}

// out[r,o] = (ascending-k fma dot) + b_pred[o]
__global__ __launch_bounds__(256) void pred_kernel(
    const float* __restrict__ rec, const float* __restrict__ W_pred,
    const float* __restrict__ b_pred, float* __restrict__ out)
{
#pragma clang fp contract(off)
    int r = blockIdx.x * 256 + threadIdx.x;   // 0..4095
    const float* f = rec + (size_t)r * 256;
    float a0 = 0.f, a1 = 0.f;
#pragma unroll 4
    for (int c = 0; c < 256; ++c) {
        float v = f[c];
        a0 = fmaf(v, W_pred[c], a0);
        a1 = fmaf(v, W_pred[256 + c], a1);
    }
    out[r * 2 + 0] = a0 + b_pred[0];
    out[r * 2 + 1] = a1 + b_pred[1];
}

extern "C" void kernel_launch(void* const* d_in, const int* in_sizes, int n_in,
                              void* d_out, int out_size, void* d_ws, size_t ws_size,
                              hipStream_t stream)
{
    const float* x        = (const float*)d_in[0];
    const float* W_in     = (const float*)d_in[1];
    const float* b_in     = (const float*)d_in[2];
    const float* beta_in  = (const float*)d_in[3];
    const float* thr_in   = (const float*)d_in[4];
    const float* W_h      = (const float*)d_in[5];
    const float* b_h      = (const float*)d_in[6];
    const float* beta_h   = (const float*)d_in[7];
    const float* thr_h    = (const float*)d_in[8];
    const float* W_h2     = (const float*)d_in[9];
    const float* b_h2     = (const float*)d_in[10];
    const float* beta_h2  = (const float*)d_in[11];
    const float* thr_h2   = (const float*)d_in[12];
    const float* W_out    = (const float*)d_in[13];
    const float* b_out    = (const float*)d_in[14];
    const float* beta_out = (const float*)d_in[15];
    const float* W_pred   = (const float*)d_in[16];
    const float* b_pred   = (const float*)d_in[17];

    char* ws = (char*)d_ws;
    unsigned short* WA = (unsigned short*)(ws + WS_WA_B);
    float* emb = (float*)(ws + WS_EMB_B);
    float* rec = (float*)(ws + WS_REC_B);

    split_weights_kernel<<<1536, 256, 0, stream>>>(W_h, W_h2, WA);
    setup_emb_kernel<<<1, 64, 0, stream>>>(emb);

    snn_main_kernel<<<NBLK, 512, 0, stream>>>(
        x, W_in, b_in, beta_in, thr_in,
        b_h, beta_h, thr_h,
        b_h2, beta_h2, thr_h2,
        W_out, b_out, beta_out,
        WA, emb, rec);

    pred_kernel<<<BB / 256, 256, 0, stream>>>(rec, W_pred, b_pred, (float*)d_out);
}

// Round 7
// 751.337 us; speedup vs baseline: 3.4481x; 2.2602x over previous
//
#include <hip/hip_runtime.h>
#include <hip/hip_bf16.h>

#define TT 64
#define BB 4096
#define HH 256
#define BMb 16             // batches per block
#define NBLK (BB / BMb)    // 256 blocks -> 1 block/CU, 8 waves (2/SIMD)

typedef short bf16x8_t __attribute__((ext_vector_type(8)));
typedef float f32x4_t  __attribute__((ext_vector_type(4)));

// d_ws layout (byte offsets)
#define WS_WA_B   0u          // split bf16 weights: 2 layers*3 parts*8kt*16nt*64lane*8j shorts = 768 KB
#define WS_EMB_B  786432u     // emb f32
#define WS_REC_B  1048576u    // rec f32 [T][B][4], 4 MB

__device__ __forceinline__ float clip01f(float v) {
    return fminf(fmaxf(v, 0.0f), 1.0f);
}

__global__ __launch_bounds__(64) void setup_emb_kernel(float* __restrict__ emb) {
    int i = threadIdx.x;
    const double sigma = 64.0 / 10.0;
    const double c = 32.0;
    double d = ((double)i - c) / sigma;
    double e = exp(-0.5 * (d * d));
    double d0 = (0.0 - c) / sigma;
    double emin = exp(-0.5 * (d0 * d0));
    emb[i] = (float)((e - emin) / (1.0 - emin));
}

// Exact 3-way split w = hi + mid + lo into bf16 parts (residuals exact).
// Pre-swizzled to A-fragment order for mfma_f32_16x16x32_bf16:
// A[m=lane&15][k=(lane>>4)*8+j], flat = ((((layer*3+part)*8+kt)*16+ntile)*64+lane)*8+j
__global__ __launch_bounds__(256) void split_weights_kernel(
    const float* __restrict__ W_h, const float* __restrict__ W_h2,
    unsigned short* __restrict__ WA)
{
    int flat = blockIdx.x * 256 + threadIdx.x;     // < 393216
    int j     = flat & 7;
    int lane  = (flat >> 3) & 63;
    int ntile = (flat >> 9) & 15;
    int kt    = (flat >> 13) & 7;
    int rest  = flat >> 16;                        // 0..5
    int part  = rest % 3;
    int layer = rest / 3;
    int k = kt * 32 + (lane >> 4) * 8 + j;
    int n = ntile * 16 + (lane & 15);
    const float* W = layer ? W_h2 : W_h;           // row-major [n][k] = W[n*256+k]
    float w = W[n * HH + k];
    __hip_bfloat16 h = __float2bfloat16(w);
    float r1 = w - __bfloat162float(h);
    __hip_bfloat16 m = __float2bfloat16(r1);
    float r2 = r1 - __bfloat162float(m);
    __hip_bfloat16 l = __float2bfloat16(r2);
    __hip_bfloat16 v = (part == 0) ? h : ((part == 1) ? m : l);
    WA[flat] = *reinterpret_cast<unsigned short*>(&v);
}

union U16x8 { uint4 u; bf16x8_t v; };

// ---- Weight pipeline WITHOUT registers: wave-local global_load_lds ring. ----
// R1-R6 lesson: named-register prefetch ALWAYS leaks a few spills (budget =
// 65536/block_threads, immovable), and even a 4-dword/thread spill creates a
// ~33MB scratch footprint (~4.1MB/XCD) that thrashes L2 and evicts the 768KB
// weight set (FETCH 4-6 GB from HBM). global_load_lds stages L2->LDS directly:
// NO destination VGPRs, nothing to spill. Each wave owns a private 2-slot x
// 6KB ring (8 waves x 12KB = 96KB); slots hold one kt-group: {part0,1,2} x
// {tile0,1} x 1KB lane-ordered A-frags, written linearly (lds base + lane*16,
// the HW's fixed pattern) and read back with ds_read_b128 at lane*16 ->
// bit-identical fragment bytes, same kt-asc/part-0,1,2 MFMA order -> output
// canary absmax 0.002365112 must be unchanged.
// Sync: vmcnt(6) counted waits (never 0 inside a phase); the compiler's
// vmcnt(0) drain at each __syncthreads guarantees the cross-phase kt0 preload
// (issued at the previous phase's step 7) has landed. Ring is wave-local ->
// no extra barriers, no cross-wave hazards.

#define AS1 __attribute__((address_space(1)))
#define AS3 __attribute__((address_space(3)))
__device__ __forceinline__ void gl16(const void* g, void* l) {
    __builtin_amdgcn_global_load_lds((AS1 const void*)g, (AS3 void*)l, 16, 0, 0);
}

// Wait until only the newest 6 gload_lds remain in flight (= previous kt's 6
// have landed). "memory" orders the following ds_reads; sched_barrier pins it.
#define WAIT6 do {                                                             \
    asm volatile("s_waitcnt vmcnt(6)" ::: "memory");                           \
    __builtin_amdgcn_sched_barrier(0);                                         \
} while (0)

// Issue the 6 loads of kt-group ktn of weight base Wc into ring slot sl.
// Wc is pre-offset by (2w)*64+lane in uint4 units (byte = *16). Strides (B):
// part 131072, kt 16384, tile 1024. Chunk order in slot: (part*2 + tile).
#define ISSUE6(Wc, ktn, sl) do {                                               \
    const char* gb_ = (const char*)(Wc) + (ktn) * 16384;                       \
    char* lb_ = myring + (sl) * 6144;                                          \
    gl16(gb_,          lb_);                                                   \
    gl16(gb_ + 1024,   lb_ + 1024);                                            \
    gl16(gb_ + 131072, lb_ + 2048);                                            \
    gl16(gb_ + 132096, lb_ + 3072);                                            \
    gl16(gb_ + 262144, lb_ + 4096);                                            \
    gl16(gb_ + 263168, lb_ + 5120);                                            \
} while (0)

// Consume slot sl for B-frag kt=ktb: 6 ds_read_b128 + 6 MFMAs.
// D0 accumulates parts 0,1,2 of tile0; D1 parts 0,1,2 of tile1 (baseline order).
#define CONSUME(sl, Bp, ktb, D0, D1) do {                                      \
    U16x8 br_; br_.u = (Bp)[(ktb) * 64];          /* spikes B-frag */          \
    U16x8 a0_, a1_, a2_, b0_, b1_, b2_;                                        \
    a0_.u = ringRd[(sl) * 384 + 0];                                            \
    b0_.u = ringRd[(sl) * 384 + 64];                                           \
    a1_.u = ringRd[(sl) * 384 + 128];                                          \
    b1_.u = ringRd[(sl) * 384 + 192];                                          \
    a2_.u = ringRd[(sl) * 384 + 256];                                          \
    b2_.u = ringRd[(sl) * 384 + 320];                                          \
    D0 = __builtin_amdgcn_mfma_f32_16x16x32_bf16(a0_.v, br_.v, D0, 0, 0, 0);   \
    D0 = __builtin_amdgcn_mfma_f32_16x16x32_bf16(a1_.v, br_.v, D0, 0, 0, 0);   \
    D0 = __builtin_amdgcn_mfma_f32_16x16x32_bf16(a2_.v, br_.v, D0, 0, 0, 0);   \
    D1 = __builtin_amdgcn_mfma_f32_16x16x32_bf16(b0_.v, br_.v, D1, 0, 0, 0);   \
    D1 = __builtin_amdgcn_mfma_f32_16x16x32_bf16(b1_.v, br_.v, D1, 0, 0, 0);   \
    D1 = __builtin_amdgcn_mfma_f32_16x16x32_bf16(b2_.v, br_.v, D1, 0, 0, 0);   \
} while (0)

// kt = 0..7 ascending. Entry invariant: slot0 holds kt0 (landed — guaranteed
// by the barrier drain of the cross-phase preload). Step k: issue kt+1 into
// slot (k+1)&1, wait counted, consume slot k&1. Step 7 preloads the NEXT
// phase's kt0 (Wn) -> invariant re-established across the barrier.
#define GPHASE(Wc, Wn, Bp, D0, D1) do {                                        \
    ISSUE6(Wc, 1, 1); WAIT6; CONSUME(0, Bp, 0, D0, D1);                        \
    ISSUE6(Wc, 2, 0); WAIT6; CONSUME(1, Bp, 1, D0, D1);                        \
    ISSUE6(Wc, 3, 1); WAIT6; CONSUME(0, Bp, 2, D0, D1);                        \
    ISSUE6(Wc, 4, 0); WAIT6; CONSUME(1, Bp, 3, D0, D1);                        \
    ISSUE6(Wc, 5, 1); WAIT6; CONSUME(0, Bp, 4, D0, D1);                        \
    ISSUE6(Wc, 6, 0); WAIT6; CONSUME(1, Bp, 5, D0, D1);                        \
    ISSUE6(Wc, 7, 1); WAIT6; CONSUME(0, Bp, 6, D0, D1);                        \
    ISSUE6(Wn, 0, 0); WAIT6; CONSUME(1, Bp, 7, D0, D1);                        \
} while (0)

// li_out walker for timestep t (wave 0 only). Ascending-k fmaf chain over
// S3F spikes (0.0/1.0): fmaf(1,w,p)=round(p+w), fmaf(0,w,p)=p -> bit-identical
// to the baseline select-add chain ("skip-zero == exact chain").
__device__ __forceinline__ void li_walker(
    const float* __restrict__ WoutS, const float (*__restrict__ S3F)[260],
    int wb, int ooc, float bto, float bo, float& m3s,
    float* __restrict__ rec, int t, int b0, int lane)
{
    if (lane < 32) {
        const float* wrow = WoutS + ooc * HH;
        const float* srow = S3F[wb];
        float p = 0.f;
#pragma unroll 8
        for (int k4 = 0; k4 < 64; ++k4) {
            float4 sv = *(const float4*)(srow + k4 * 4);
            float4 wv = *(const float4*)(wrow + k4 * 4);
            p = fmaf(sv.x, wv.x, p);
            p = fmaf(sv.y, wv.y, p);
            p = fmaf(sv.z, wv.z, p);
            p = fmaf(sv.w, wv.w, p);
        }
        float mm3 = fmaf(bto, m3s, p);
        mm3 = mm3 + bo;
        m3s = mm3;
        float spk = ((m3s - 1.0f) > 0.f) ? 1.f : 0.f;
        float om3 = __shfl_xor(m3s, 16, 64);
        float osp = __shfl_xor(spk, 16, 64);
        if (lane < 16) {
            *(float4*)(rec + ((size_t)t * BB + b0 + wb) * 4) =
                make_float4(spk, osp, m3s, om3);
        }
    }
}

__global__ __launch_bounds__(512) void snn_main_kernel(
    const float* __restrict__ x,
    const float* __restrict__ W_in, const float* __restrict__ b_in,
    const float* __restrict__ beta_in, const float* __restrict__ thr_in,
    const float* __restrict__ b_h, const float* __restrict__ beta_h, const float* __restrict__ thr_h,
    const float* __restrict__ b_h2, const float* __restrict__ beta_h2, const float* __restrict__ thr_h2,
    const float* __restrict__ W_out, const float* __restrict__ b_out, const float* __restrict__ beta_out,
    const unsigned short* __restrict__ WA, const float* __restrict__ emb,
    float* __restrict__ rec)
{
#pragma clang fp contract(off)   // all contraction EXPLICIT via fmaf
    const int tid = threadIdx.x;
    const int w = tid >> 6;       // wave 0..7: owns n-tiles 2w, 2w+1
    const int lane = tid & 63;
    const int b = lane & 15;      // batch column (D col = lane&15)
    const int g = lane >> 4;      // row group   (D row = g*4+reg)
    const int b0 = blockIdx.x * BMb;

    __shared__ unsigned short sbuf1[8 * 64 * 8];            // B-frags spikes layer1 (8 KB)
    __shared__ unsigned short sbuf2[8 * 64 * 8];            // B-frags spikes layer2 (8 KB)
    __shared__ __align__(16) float S3F[16][260];            // layer-3 spikes [batch][n]
    __shared__ __align__(16) float WoutS[2 * HH];
    __shared__ float4 PL1a[HH];   // {wi0, wi1, wi2, b_in}
    __shared__ float2 PL1b[HH];   // {bt1c, th1}
    __shared__ float4 PL2[HH];    // {b_h,  bt2c, th2, -}
    __shared__ float4 PL3[HH];    // {b_h2, bt3c, th3, -}
    __shared__ float  xs[TT][BMb][3];   // staged x slice (12 KB)
    __shared__ float  embS[TT];
    // Wave-local weight ring: 8 waves x 2 slots x 6KB. Total static ~156.5KB
    // (<160KB). Also pins occupancy at 1 block/CU in HW (grid=256 anyway).
    __shared__ __align__(16) char ring[8 * 2 * 6144];       // 96 KB

    char* myring = ring + w * 12288;                        // wave-uniform dest base
    const uint4* ringRd = (const uint4*)(ring + w * 12288 + lane * 16);

    WoutS[tid] = W_out[tid];      // 512 threads = 512 elems
    if (tid < HH) {
        int n = tid;
        PL1a[n] = make_float4(W_in[n * 3], W_in[n * 3 + 1], W_in[n * 3 + 2], b_in[n]);
        PL1b[n] = make_float2(clip01f(beta_in[n]), thr_in[n]);
        PL2[n]  = make_float4(b_h[n],  clip01f(beta_h[n]),  thr_h[n],  0.f);
        PL3[n]  = make_float4(b_h2[n], clip01f(beta_h2[n]), thr_h2[n], 0.f);
    }
    if (tid < TT) embS[tid] = emb[tid];
#pragma unroll
    for (int i = tid; i < TT * BMb; i += 512) {   // 2 iters: 64 t * 16 batches
        int ts = i >> 4, bb = i & 15;
        const float* xp = x + ((size_t)ts * BB + b0 + bb) * 3;
        xs[ts][bb][0] = xp[0];
        xs[ts][bb][1] = xp[1];
        xs[ts][bb][2] = xp[2];
    }

    // this thread's 8 neurons: n = (2w+u)*16 + g*4 + r, u in {0,1}
    const int nb0 = w * 32 + g * 4;

    float m1[2][4], m2[2][4], m4[2][4];
#pragma unroll
    for (int u = 0; u < 2; ++u)
#pragma unroll
        for (int r = 0; r < 4; ++r) { m1[u][r] = 0.f; m2[u][r] = 0.f; m4[u][r] = 0.f; }

    // spike -> B-frag LDS address for tile nt=2w+u (one b64 per thread per tile):
    // k=n: kt2 = nt>>1 = w, q = (nt&1)*2 + (g>>1), dst_lane = q*16+b, j0 = (g&1)*4
    // u=0 at sb0, u=1 at sb0+256 (q += 2 -> +32 lanes * 8 shorts)
    const int sb0 = ((w * 64 + ((g >> 1) * 16 + b)) * 8 + (g & 1) * 4);

    // li_out walker state (wave 0, lanes 0..31): wb = batch, ooc = channel
    const int wb = lane & 15;
    const int ooc = (lane >> 4) & 1;
    float bto = clip01f(beta_out[ooc]);
    float bo = b_out[ooc];
    float m3s = 0.f;

    // A-fragment bases, pre-offset by this thread's (tile-pair, lane); uint4
    // units. flat = (((layer*3+part)*8+kt)*16 + ntile)*64 + lane; layer stride
    // 24576 u4. ISSUE6 adds part/kt/tile byte strides on top.
    const uint4* W2 = (const uint4*)WA + (size_t)(2 * w) * 64 + lane;   // layer2
    const uint4* W3 = W2 + 24576;                                       // layer3
    const uint4* Bp1 = (const uint4*)sbuf1 + lane;
    const uint4* Bp2 = (const uint4*)sbuf2 + lane;

    ISSUE6(W2, 0, 0);             // t=0 layer-2 kt0 in flight before the loop

    __syncthreads();              // LDS init visible; also drains the preload

    for (int t = 0; t < TT; ++t) {
        // ---- phase A: layer 1, exact f32 chain + contracted LIF; spikes -> B-frag LDS ----
        {
            float et = embS[t];
            float xe0 = xs[t][b][0] * et;
            float xe1 = xs[t][b][1] * et;
            float xe2 = xs[t][b][2] * et;
            unsigned sp[2][4];
#pragma unroll
            for (int u = 0; u < 2; ++u)
#pragma unroll
            for (int r = 0; r < 4; ++r) {
                int n = nb0 + u * 16 + r;
                float4 pa = PL1a[n];
                float2 pb = PL1b[n];
                float a1 = xe0 * pa.x;
                a1 = fmaf(xe1, pa.y, a1);
                a1 = fmaf(xe2, pa.z, a1);
                float cur = a1 + pa.w;
                float rf = ((m1[u][r] - pb.y) > 0.f) ? 1.f : 0.f;  // reset from PREVIOUS mem
                float mm = fmaf(pb.x, m1[u][r], cur);              // contracted: beta*m + cur
                mm = fmaf(-rf, pb.y, mm);                          // contracted: - reset*thr
                m1[u][r] = mm;
                sp[u][r] = ((mm - pb.y) > 0.f) ? 0x3F80u : 0u;     // bf16 1.0 / 0.0
            }
            *(uint2*)(sbuf1 + sb0)       = make_uint2(sp[0][0] | (sp[0][1] << 16), sp[0][2] | (sp[0][3] << 16));
            *(uint2*)(sbuf1 + sb0 + 256) = make_uint2(sp[1][0] | (sp[1][1] << 16), sp[1][2] | (sp[1][3] << 16));
        }
        __syncthreads();   // BAR1 (drains vmcnt -> phase-B kt0 landed)

        // ---- phase B: wave0 runs walker(t-1) first (hides under others' MFMA/VMEM);
        //      then layer-2 MFMA (2 tiles) fed by the gload_lds ring; epilogue LIF ----
        if (w == 0 && t > 0)
            li_walker(WoutS, S3F, wb, ooc, bto, bo, m3s, rec, t - 1, b0, lane);
        {
            f32x4_t D0 = (f32x4_t){0.f, 0.f, 0.f, 0.f};
            f32x4_t D1 = (f32x4_t){0.f, 0.f, 0.f, 0.f};
            GPHASE(W2, W3, Bp1, D0, D1);             // step7 preloads layer-3 kt0
            unsigned sp[2][4];
#pragma unroll
            for (int r = 0; r < 4; ++r) {
                int n0 = nb0 + r;
                float4 p2 = PL2[n0];
                float cur = D0[r] + p2.x;
                float rf = ((m2[0][r] - p2.z) > 0.f) ? 1.f : 0.f;
                float mm = fmaf(p2.y, m2[0][r], cur);
                mm = fmaf(-rf, p2.z, mm);
                m2[0][r] = mm;
                sp[0][r] = ((mm - p2.z) > 0.f) ? 0x3F80u : 0u;
            }
#pragma unroll
            for (int r = 0; r < 4; ++r) {
                int n1 = nb0 + 16 + r;
                float4 p2 = PL2[n1];
                float cur = D1[r] + p2.x;
                float rf = ((m2[1][r] - p2.z) > 0.f) ? 1.f : 0.f;
                float mm = fmaf(p2.y, m2[1][r], cur);
                mm = fmaf(-rf, p2.z, mm);
                m2[1][r] = mm;
                sp[1][r] = ((mm - p2.z) > 0.f) ? 0x3F80u : 0u;
            }
            *(uint2*)(sbuf2 + sb0)       = make_uint2(sp[0][0] | (sp[0][1] << 16), sp[0][2] | (sp[0][3] << 16));
            *(uint2*)(sbuf2 + sb0 + 256) = make_uint2(sp[1][0] | (sp[1][1] << 16), sp[1][2] | (sp[1][3] << 16));
        }
        __syncthreads();   // BAR2 (drains vmcnt -> phase-C kt0 landed; fences walker's S3F reads)

        // ---- phase C: layer-3 MFMA (2 tiles); epilogue LIF -> S3F spike floats ----
        {
            f32x4_t E0 = (f32x4_t){0.f, 0.f, 0.f, 0.f};
            f32x4_t E1 = (f32x4_t){0.f, 0.f, 0.f, 0.f};
            GPHASE(W3, W2, Bp2, E0, E1);             // step7 preloads next-t layer-2 kt0
            float s3v[2][4];
#pragma unroll
            for (int r = 0; r < 4; ++r) {
                int n0 = nb0 + r;
                float4 p3 = PL3[n0];
                float cur = E0[r] + p3.x;
                float rf = ((m4[0][r] - p3.z) > 0.f) ? 1.f : 0.f;
                float mm = fmaf(p3.y, m4[0][r], cur);
                mm = fmaf(-rf, p3.z, mm);
                m4[0][r] = mm;
                s3v[0][r] = ((mm - p3.z) > 0.f) ? 1.0f : 0.0f;
            }
#pragma unroll
            for (int r = 0; r < 4; ++r) {
                int n1 = nb0 + 16 + r;
                float4 p3 = PL3[n1];
                float cur = E1[r] + p3.x;
                float rf = ((m4[1][r] - p3.z) > 0.f) ? 1.f : 0.f;
                float mm = fmaf(p3.y, m4[1][r], cur);
                mm = fmaf(-rf, p3.z, mm);
                m4[1][r] = mm;
                s3v[1][r] = ((mm - p3.z) > 0.f) ? 1.0f : 0.0f;
            }
            *(float4*)(&S3F[b][nb0])      = make_float4(s3v[0][0], s3v[0][1], s3v[0][2], s3v[0][3]);
            *(float4*)(&S3F[b][nb0 + 16]) = make_float4(s3v[1][0], s3v[1][1], s3v[1][2], s3v[1][3]);
        }
        __syncthreads();   // BAR3
    }

    // final walker for t = 63
    if (w == 0)
        li_walker(WoutS, S3F, wb, ooc, bto, bo, m3s, rec, TT - 1, b0, lane);
}

// out[r,o] = (ascending-k fma dot) + b_pred[o]
__global__ __launch_bounds__(256) void pred_kernel(
    const float* __restrict__ rec, const float* __restrict__ W_pred,
    const float* __restrict__ b_pred, float* __restrict__ out)
{
#pragma clang fp contract(off)
    int r = blockIdx.x * 256 + threadIdx.x;   // 0..4095
    const float* f = rec + (size_t)r * 256;
    float a0 = 0.f, a1 = 0.f;
#pragma unroll 4
    for (int c = 0; c < 256; ++c) {
        float v = f[c];
        a0 = fmaf(v, W_pred[c], a0);
        a1 = fmaf(v, W_pred[256 + c], a1);
    }
    out[r * 2 + 0] = a0 + b_pred[0];
    out[r * 2 + 1] = a1 + b_pred[1];
}

extern "C" void kernel_launch(void* const* d_in, const int* in_sizes, int n_in,
                              void* d_out, int out_size, void* d_ws, size_t ws_size,
                              hipStream_t stream)
{
    const float* x        = (const float*)d_in[0];
    const float* W_in     = (const float*)d_in[1];
    const float* b_in     = (const float*)d_in[2];
    const float* beta_in  = (const float*)d_in[3];
    const float* thr_in   = (const float*)d_in[4];
    const float* W_h      = (const float*)d_in[5];
    const float* b_h      = (const float*)d_in[6];
    const float* beta_h   = (const float*)d_in[7];
    const float* thr_h    = (const float*)d_in[8];
    const float* W_h2     = (const float*)d_in[9];
    const float* b_h2     = (const float*)d_in[10];
    const float* beta_h2  = (const float*)d_in[11];
    const float* thr_h2   = (const float*)d_in[12];
    const float* W_out    = (const float*)d_in[13];
    const float* b_out    = (const float*)d_in[14];
    const float* beta_out = (const float*)d_in[15];
    const float* W_pred   = (const float*)d_in[16];
    const float* b_pred   = (const float*)d_in[17];

    char* ws = (char*)d_ws;
    unsigned short* WA = (unsigned short*)(ws + WS_WA_B);
    float* emb = (float*)(ws + WS_EMB_B);
    float* rec = (float*)(ws + WS_REC_B);

    split_weights_kernel<<<1536, 256, 0, stream>>>(W_h, W_h2, WA);
    setup_emb_kernel<<<1, 64, 0, stream>>>(emb);

    snn_main_kernel<<<NBLK, 512, 0, stream>>>(
        x, W_in, b_in, beta_in, thr_in,
        b_h, beta_h, thr_h,
        b_h2, beta_h2, thr_h2,
        W_out, b_out, beta_out,
        WA, emb, rec);

    pred_kernel<<<BB / 256, 256, 0, stream>>>(rec, W_pred, b_pred, (float*)d_out);
}

// Round 8
// 741.866 us; speedup vs baseline: 3.4921x; 1.0128x over previous
//
#include <hip/hip_runtime.h>
#include <hip/hip_bf16.h>

#define TT 64
#define BB 4096
#define HH 256
#define BMb 16             // batches per block
#define NBLK (BB / BMb)    // 256 blocks -> 1 block/CU, 8 waves (2/SIMD)

typedef short bf16x8_t __attribute__((ext_vector_type(8)));
typedef float f32x4_t  __attribute__((ext_vector_type(4)));

// d_ws layout (byte offsets)
#define WS_WA_B   0u          // split bf16 weights: 2 layers*3 parts*8kt*16nt*64lane*8j shorts = 768 KB
#define WS_EMB_B  786432u     // emb f32
#define WS_REC_B  1048576u    // rec f32 [T][B][4], 4 MB

__device__ __forceinline__ float clip01f(float v) {
    return fminf(fmaxf(v, 0.0f), 1.0f);
}

__global__ __launch_bounds__(64) void setup_emb_kernel(float* __restrict__ emb) {
    int i = threadIdx.x;
    const double sigma = 64.0 / 10.0;
    const double c = 32.0;
    double d = ((double)i - c) / sigma;
    double e = exp(-0.5 * (d * d));
    double d0 = (0.0 - c) / sigma;
    double emin = exp(-0.5 * (d0 * d0));
    emb[i] = (float)((e - emin) / (1.0 - emin));
}

// Exact 3-way split w = hi + mid + lo into bf16 parts (residuals exact).
// Pre-swizzled to A-fragment order for mfma_f32_16x16x32_bf16:
// A[m=lane&15][k=(lane>>4)*8+j], flat = ((((layer*3+part)*8+kt)*16+ntile)*64+lane)*8+j
__global__ __launch_bounds__(256) void split_weights_kernel(
    const float* __restrict__ W_h, const float* __restrict__ W_h2,
    unsigned short* __restrict__ WA)
{
    int flat = blockIdx.x * 256 + threadIdx.x;     // < 393216
    int j     = flat & 7;
    int lane  = (flat >> 3) & 63;
    int ntile = (flat >> 9) & 15;
    int kt    = (flat >> 13) & 7;
    int rest  = flat >> 16;                        // 0..5
    int part  = rest % 3;
    int layer = rest / 3;
    int k = kt * 32 + (lane >> 4) * 8 + j;
    int n = ntile * 16 + (lane & 15);
    const float* W = layer ? W_h2 : W_h;           // row-major [n][k] = W[n*256+k]
    float w = W[n * HH + k];
    __hip_bfloat16 h = __float2bfloat16(w);
    float r1 = w - __bfloat162float(h);
    __hip_bfloat16 m = __float2bfloat16(r1);
    float r2 = r1 - __bfloat162float(m);
    __hip_bfloat16 l = __float2bfloat16(r2);
    __hip_bfloat16 v = (part == 0) ? h : ((part == 1) ? m : l);
    WA[flat] = *reinterpret_cast<unsigned short*>(&v);
}

union U16x8 { uint4 u; bf16x8_t v; };

// ---- Weight pipeline: wave-local global_load_lds ring, DEPTH-2 lookahead. ----
// R7 (depth-1, issue-then-wait) reached 727us steady: FETCH 10.7MB (weights
// L2-resident), no scratch — but 75% of cycles still stall: each step waited on
// loads issued only ~1 consume (~170cy) earlier vs contended L2 latency of
// several hundred cycles. Depth-2 restructure (SAME 2x6KB slots, no new LDS or
// VGPRs): per step, wait-counted -> ds_read the landed slot -> lgkmcnt(0) (data
// in regs) -> issue kt+2 into the slot just vacated -> MFMAs. Loads get ~2 full
// steps to land; prologue pre-issues kt0 AND kt1. Issue-AFTER-read also removes
// the may-alias (gload_lds -> ds_read same slot) pattern that invites the
// compiler's waitcnt pass to over-wait.
// Fragment bytes, kt-asc / part-0,1,2 per-D accumulation order unchanged ->
// bit-identical output (canary absmax 0.002365112).

#define AS1 __attribute__((address_space(1)))
#define AS3 __attribute__((address_space(3)))
__device__ __forceinline__ void gl16(const void* g, void* l) {
    __builtin_amdgcn_global_load_lds((AS1 const void*)g, (AS3 void*)l, 16, 0, 0);
}

// Issue the 6 loads of kt-group ktn of weight base Wc into ring slot sl.
// Wc is pre-offset by (2w)*64+lane in uint4 units (byte = *16). Strides (B):
// part 131072, kt 16384, tile 1024. Chunk order in slot: (part*2 + tile).
#define ISSUE6(Wc, ktn, sl) do {                                               \
    const char* gb_ = (const char*)(Wc) + (ktn) * 16384;                       \
    char* lb_ = myring + (sl) * 6144;                                          \
    gl16(gb_,          lb_);                                                   \
    gl16(gb_ + 1024,   lb_ + 1024);                                            \
    gl16(gb_ + 131072, lb_ + 2048);                                            \
    gl16(gb_ + 132096, lb_ + 3072);                                            \
    gl16(gb_ + 262144, lb_ + 4096);                                            \
    gl16(gb_ + 263168, lb_ + 5120);                                            \
} while (0)

// Depth-2 step: consume slot sl (kt=ktb for B-frags), refill it with (Wi,kti).
// Order enforced: vmcnt(6) [kt_b landed; the newer 6 stay in flight] ->
// ds_read_b128 x7 -> lgkmcnt(0)+SB [regs valid; slot dead] -> ISSUE6 [kt+2
// into dead slot] -> SB -> 6 MFMAs (parts 0,1,2 per tile = baseline order).
#define STEPD2(sl, Bp, ktb, Wi, kti, D0, D1) do {                              \
    asm volatile("s_waitcnt vmcnt(6)" ::: "memory");                           \
    __builtin_amdgcn_sched_barrier(0);                                         \
    U16x8 br_, a0_, a1_, a2_, b0_, b1_, b2_;                                   \
    br_.u = (Bp)[(ktb) * 64];                     /* spikes B-frag */          \
    a0_.u = ringRd[(sl) * 384 + 0];                                            \
    b0_.u = ringRd[(sl) * 384 + 64];                                           \
    a1_.u = ringRd[(sl) * 384 + 128];                                          \
    b1_.u = ringRd[(sl) * 384 + 192];                                          \
    a2_.u = ringRd[(sl) * 384 + 256];                                          \
    b2_.u = ringRd[(sl) * 384 + 320];                                          \
    asm volatile("s_waitcnt lgkmcnt(0)" ::: "memory");                         \
    __builtin_amdgcn_sched_barrier(0);                                         \
    ISSUE6(Wi, kti, sl);                                                       \
    __builtin_amdgcn_sched_barrier(0);                                         \
    D0 = __builtin_amdgcn_mfma_f32_16x16x32_bf16(a0_.v, br_.v, D0, 0, 0, 0);   \
    D0 = __builtin_amdgcn_mfma_f32_16x16x32_bf16(a1_.v, br_.v, D0, 0, 0, 0);   \
    D0 = __builtin_amdgcn_mfma_f32_16x16x32_bf16(a2_.v, br_.v, D0, 0, 0, 0);   \
    D1 = __builtin_amdgcn_mfma_f32_16x16x32_bf16(b0_.v, br_.v, D1, 0, 0, 0);   \
    D1 = __builtin_amdgcn_mfma_f32_16x16x32_bf16(b1_.v, br_.v, D1, 0, 0, 0);   \
    D1 = __builtin_amdgcn_mfma_f32_16x16x32_bf16(b2_.v, br_.v, D1, 0, 0, 0);   \
} while (0)

// kt = 0..7 ascending. Entry invariant: slot0 = kt0, slot1 = kt1 (both landed
// — the previous barrier's vmcnt(0) drain guarantees it; they were issued 1-2
// steps before that barrier so the drain is cheap). Step k consumes kt_k from
// slot(k&1) and refills with kt_{k+2}; steps 6,7 refill with the NEXT phase's
// kt0,kt1 -> invariant re-established across the barrier.
#define GPHASE(Wc, Wn, Bp, D0, D1) do {                                        \
    STEPD2(0, Bp, 0, Wc, 2, D0, D1);                                           \
    STEPD2(1, Bp, 1, Wc, 3, D0, D1);                                           \
    STEPD2(0, Bp, 2, Wc, 4, D0, D1);                                           \
    STEPD2(1, Bp, 3, Wc, 5, D0, D1);                                           \
    STEPD2(0, Bp, 4, Wc, 6, D0, D1);                                           \
    STEPD2(1, Bp, 5, Wc, 7, D0, D1);                                           \
    STEPD2(0, Bp, 6, Wn, 0, D0, D1);                                           \
    STEPD2(1, Bp, 7, Wn, 1, D0, D1);                                           \
} while (0)

// li_out walker for timestep t (wave 0 only). Ascending-k fmaf chain over
// S3F spikes (0.0/1.0): fmaf(1,w,p)=round(p+w), fmaf(0,w,p)=p -> bit-identical
// to the baseline select-add chain ("skip-zero == exact chain").
__device__ __forceinline__ void li_walker(
    const float* __restrict__ WoutS, const float (*__restrict__ S3F)[260],
    int wb, int ooc, float bto, float bo, float& m3s,
    float* __restrict__ rec, int t, int b0, int lane)
{
    if (lane < 32) {
        const float* wrow = WoutS + ooc * HH;
        const float* srow = S3F[wb];
        float p = 0.f;
#pragma unroll 8
        for (int k4 = 0; k4 < 64; ++k4) {
            float4 sv = *(const float4*)(srow + k4 * 4);
            float4 wv = *(const float4*)(wrow + k4 * 4);
            p = fmaf(sv.x, wv.x, p);
            p = fmaf(sv.y, wv.y, p);
            p = fmaf(sv.z, wv.z, p);
            p = fmaf(sv.w, wv.w, p);
        }
        float mm3 = fmaf(bto, m3s, p);
        mm3 = mm3 + bo;
        m3s = mm3;
        float spk = ((m3s - 1.0f) > 0.f) ? 1.f : 0.f;
        float om3 = __shfl_xor(m3s, 16, 64);
        float osp = __shfl_xor(spk, 16, 64);
        if (lane < 16) {
            *(float4*)(rec + ((size_t)t * BB + b0 + wb) * 4) =
                make_float4(spk, osp, m3s, om3);
        }
    }
}

__global__ __launch_bounds__(512) void snn_main_kernel(
    const float* __restrict__ x,
    const float* __restrict__ W_in, const float* __restrict__ b_in,
    const float* __restrict__ beta_in, const float* __restrict__ thr_in,
    const float* __restrict__ b_h, const float* __restrict__ beta_h, const float* __restrict__ thr_h,
    const float* __restrict__ b_h2, const float* __restrict__ beta_h2, const float* __restrict__ thr_h2,
    const float* __restrict__ W_out, const float* __restrict__ b_out, const float* __restrict__ beta_out,
    const unsigned short* __restrict__ WA, const float* __restrict__ emb,
    float* __restrict__ rec)
{
#pragma clang fp contract(off)   // all contraction EXPLICIT via fmaf
    const int tid = threadIdx.x;
    const int w = tid >> 6;       // wave 0..7: owns n-tiles 2w, 2w+1
    const int lane = tid & 63;
    const int b = lane & 15;      // batch column (D col = lane&15)
    const int g = lane >> 4;      // row group   (D row = g*4+reg)
    const int b0 = blockIdx.x * BMb;

    __shared__ unsigned short sbuf1[8 * 64 * 8];            // B-frags spikes layer1 (8 KB)
    __shared__ unsigned short sbuf2[8 * 64 * 8];            // B-frags spikes layer2 (8 KB)
    __shared__ __align__(16) float S3F[16][260];            // layer-3 spikes [batch][n]
    __shared__ __align__(16) float WoutS[2 * HH];
    __shared__ float4 PL1a[HH];   // {wi0, wi1, wi2, b_in}
    __shared__ float2 PL1b[HH];   // {bt1c, th1}
    __shared__ float4 PL2[HH];    // {b_h,  bt2c, th2, -}
    __shared__ float4 PL3[HH];    // {b_h2, bt3c, th3, -}
    __shared__ float  xs[TT][BMb][3];   // staged x slice (12 KB)
    __shared__ float  embS[TT];
    // Wave-local weight ring: 8 waves x 2 slots x 6KB. Total static ~156.5KB
    // (<160KB). Also pins occupancy at 1 block/CU in HW (grid=256 anyway).
    __shared__ __align__(16) char ring[8 * 2 * 6144];       // 96 KB

    char* myring = ring + w * 12288;                        // wave-uniform dest base
    const uint4* ringRd = (const uint4*)(ring + w * 12288 + lane * 16);

    WoutS[tid] = W_out[tid];      // 512 threads = 512 elems
    if (tid < HH) {
        int n = tid;
        PL1a[n] = make_float4(W_in[n * 3], W_in[n * 3 + 1], W_in[n * 3 + 2], b_in[n]);
        PL1b[n] = make_float2(clip01f(beta_in[n]), thr_in[n]);
        PL2[n]  = make_float4(b_h[n],  clip01f(beta_h[n]),  thr_h[n],  0.f);
        PL3[n]  = make_float4(b_h2[n], clip01f(beta_h2[n]), thr_h2[n], 0.f);
    }
    if (tid < TT) embS[tid] = emb[tid];
#pragma unroll
    for (int i = tid; i < TT * BMb; i += 512) {   // 2 iters: 64 t * 16 batches
        int ts = i >> 4, bb = i & 15;
        const float* xp = x + ((size_t)ts * BB + b0 + bb) * 3;
        xs[ts][bb][0] = xp[0];
        xs[ts][bb][1] = xp[1];
        xs[ts][bb][2] = xp[2];
    }

    // this thread's 8 neurons: n = (2w+u)*16 + g*4 + r, u in {0,1}
    const int nb0 = w * 32 + g * 4;

    float m1[2][4], m2[2][4], m4[2][4];
#pragma unroll
    for (int u = 0; u < 2; ++u)
#pragma unroll
        for (int r = 0; r < 4; ++r) { m1[u][r] = 0.f; m2[u][r] = 0.f; m4[u][r] = 0.f; }

    // spike -> B-frag LDS address for tile nt=2w+u (one b64 per thread per tile):
    // k=n: kt2 = nt>>1 = w, q = (nt&1)*2 + (g>>1), dst_lane = q*16+b, j0 = (g&1)*4
    // u=0 at sb0, u=1 at sb0+256 (q += 2 -> +32 lanes * 8 shorts)
    const int sb0 = ((w * 64 + ((g >> 1) * 16 + b)) * 8 + (g & 1) * 4);

    // li_out walker state (wave 0, lanes 0..31): wb = batch, ooc = channel
    const int wb = lane & 15;
    const int ooc = (lane >> 4) & 1;
    float bto = clip01f(beta_out[ooc]);
    float bo = b_out[ooc];
    float m3s = 0.f;

    // A-fragment bases, pre-offset by this thread's (tile-pair, lane); uint4
    // units. flat = (((layer*3+part)*8+kt)*16 + ntile)*64 + lane; layer stride
    // 24576 u4. ISSUE6 adds part/kt/tile byte strides on top.
    const uint4* W2 = (const uint4*)WA + (size_t)(2 * w) * 64 + lane;   // layer2
    const uint4* W3 = W2 + 24576;                                       // layer3
    const uint4* Bp1 = (const uint4*)sbuf1 + lane;
    const uint4* Bp2 = (const uint4*)sbuf2 + lane;

    ISSUE6(W2, 0, 0);             // t=0 layer-2 kt0 in flight before the loop
    ISSUE6(W2, 1, 1);             // t=0 layer-2 kt1 in flight (depth-2 invariant)

    __syncthreads();              // LDS init visible; also drains the preloads

    for (int t = 0; t < TT; ++t) {
        // ---- phase A: layer 1, exact f32 chain + contracted LIF; spikes -> B-frag LDS ----
        {
            float et = embS[t];
            float xe0 = xs[t][b][0] * et;
            float xe1 = xs[t][b][1] * et;
            float xe2 = xs[t][b][2] * et;
            unsigned sp[2][4];
#pragma unroll
            for (int u = 0; u < 2; ++u)
#pragma unroll
            for (int r = 0; r < 4; ++r) {
                int n = nb0 + u * 16 + r;
                float4 pa = PL1a[n];
                float2 pb = PL1b[n];
                float a1 = xe0 * pa.x;
                a1 = fmaf(xe1, pa.y, a1);
                a1 = fmaf(xe2, pa.z, a1);
                float cur = a1 + pa.w;
                float rf = ((m1[u][r] - pb.y) > 0.f) ? 1.f : 0.f;  // reset from PREVIOUS mem
                float mm = fmaf(pb.x, m1[u][r], cur);              // contracted: beta*m + cur
                mm = fmaf(-rf, pb.y, mm);                          // contracted: - reset*thr
                m1[u][r] = mm;
                sp[u][r] = ((mm - pb.y) > 0.f) ? 0x3F80u : 0u;     // bf16 1.0 / 0.0
            }
            *(uint2*)(sbuf1 + sb0)       = make_uint2(sp[0][0] | (sp[0][1] << 16), sp[0][2] | (sp[0][3] << 16));
            *(uint2*)(sbuf1 + sb0 + 256) = make_uint2(sp[1][0] | (sp[1][1] << 16), sp[1][2] | (sp[1][3] << 16));
        }
        __syncthreads();   // BAR1 (drains vmcnt -> phase-B kt0,kt1 landed)

        // ---- phase B: wave0 runs walker(t-1) first (hides under others' MFMA/VMEM);
        //      then layer-2 MFMA (2 tiles) fed by the depth-2 ring; epilogue LIF ----
        if (w == 0 && t > 0)
            li_walker(WoutS, S3F, wb, ooc, bto, bo, m3s, rec, t - 1, b0, lane);
        {
            f32x4_t D0 = (f32x4_t){0.f, 0.f, 0.f, 0.f};
            f32x4_t D1 = (f32x4_t){0.f, 0.f, 0.f, 0.f};
            GPHASE(W2, W3, Bp1, D0, D1);             // steps 6,7 preload layer-3 kt0,kt1
            unsigned sp[2][4];
#pragma unroll
            for (int r = 0; r < 4; ++r) {
                int n0 = nb0 + r;
                float4 p2 = PL2[n0];
                float cur = D0[r] + p2.x;
                float rf = ((m2[0][r] - p2.z) > 0.f) ? 1.f : 0.f;
                float mm = fmaf(p2.y, m2[0][r], cur);
                mm = fmaf(-rf, p2.z, mm);
                m2[0][r] = mm;
                sp[0][r] = ((mm - p2.z) > 0.f) ? 0x3F80u : 0u;
            }
#pragma unroll
            for (int r = 0; r < 4; ++r) {
                int n1 = nb0 + 16 + r;
                float4 p2 = PL2[n1];
                float cur = D1[r] + p2.x;
                float rf = ((m2[1][r] - p2.z) > 0.f) ? 1.f : 0.f;
                float mm = fmaf(p2.y, m2[1][r], cur);
                mm = fmaf(-rf, p2.z, mm);
                m2[1][r] = mm;
                sp[1][r] = ((mm - p2.z) > 0.f) ? 0x3F80u : 0u;
            }
            *(uint2*)(sbuf2 + sb0)       = make_uint2(sp[0][0] | (sp[0][1] << 16), sp[0][2] | (sp[0][3] << 16));
            *(uint2*)(sbuf2 + sb0 + 256) = make_uint2(sp[1][0] | (sp[1][1] << 16), sp[1][2] | (sp[1][3] << 16));
        }
        __syncthreads();   // BAR2 (drains vmcnt -> phase-C kt0,kt1 landed; fences walker's S3F reads)

        // ---- phase C: layer-3 MFMA (2 tiles); epilogue LIF -> S3F spike floats ----
        {
            f32x4_t E0 = (f32x4_t){0.f, 0.f, 0.f, 0.f};
            f32x4_t E1 = (f32x4_t){0.f, 0.f, 0.f, 0.f};
            GPHASE(W3, W2, Bp2, E0, E1);             // steps 6,7 preload next-t layer-2 kt0,kt1
            float s3v[2][4];
#pragma unroll
            for (int r = 0; r < 4; ++r) {
                int n0 = nb0 + r;
                float4 p3 = PL3[n0];
                float cur = E0[r] + p3.x;
                float rf = ((m4[0][r] - p3.z) > 0.f) ? 1.f : 0.f;
                float mm = fmaf(p3.y, m4[0][r], cur);
                mm = fmaf(-rf, p3.z, mm);
                m4[0][r] = mm;
                s3v[0][r] = ((mm - p3.z) > 0.f) ? 1.0f : 0.0f;
            }
#pragma unroll
            for (int r = 0; r < 4; ++r) {
                int n1 = nb0 + 16 + r;
                float4 p3 = PL3[n1];
                float cur = E1[r] + p3.x;
                float rf = ((m4[1][r] - p3.z) > 0.f) ? 1.f : 0.f;
                float mm = fmaf(p3.y, m4[1][r], cur);
                mm = fmaf(-rf, p3.z, mm);
                m4[1][r] = mm;
                s3v[1][r] = ((mm - p3.z) > 0.f) ? 1.0f : 0.0f;
            }
            *(float4*)(&S3F[b][nb0])      = make_float4(s3v[0][0], s3v[0][1], s3v[0][2], s3v[0][3]);
            *(float4*)(&S3F[b][nb0 + 16]) = make_float4(s3v[1][0], s3v[1][1], s3v[1][2], s3v[1][3]);
        }
        __syncthreads();   // BAR3
    }

    // final walker for t = 63
    if (w == 0)
        li_walker(WoutS, S3F, wb, ooc, bto, bo, m3s, rec, TT - 1, b0, lane);
}

// out[r,o] = (ascending-k fma dot) + b_pred[o]
__global__ __launch_bounds__(256) void pred_kernel(
    const float* __restrict__ rec, const float* __restrict__ W_pred,
    const float* __restrict__ b_pred, float* __restrict__ out)
{
#pragma clang fp contract(off)
    int r = blockIdx.x * 256 + threadIdx.x;   // 0..4095
    const float* f = rec + (size_t)r * 256;
    float a0 = 0.f, a1 = 0.f;
#pragma unroll 4
    for (int c = 0; c < 256; ++c) {
        float v = f[c];
        a0 = fmaf(v, W_pred[c], a0);
        a1 = fmaf(v, W_pred[256 + c], a1);
    }
    out[r * 2 + 0] = a0 + b_pred[0];
    out[r * 2 + 1] = a1 + b_pred[1];
}

extern "C" void kernel_launch(void* const* d_in, const int* in_sizes, int n_in,
                              void* d_out, int out_size, void* d_ws, size_t ws_size,
                              hipStream_t stream)
{
    const float* x        = (const float*)d_in[0];
    const float* W_in     = (const float*)d_in[1];
    const float* b_in     = (const float*)d_in[2];
    const float* beta_in  = (const float*)d_in[3];
    const float* thr_in   = (const float*)d_in[4];
    const float* W_h      = (const float*)d_in[5];
    const float* b_h      = (const float*)d_in[6];
    const float* beta_h   = (const float*)d_in[7];
    const float* thr_h    = (const float*)d_in[8];
    const float* W_h2     = (const float*)d_in[9];
    const float* b_h2     = (const float*)d_in[10];
    const float* beta_h2  = (const float*)d_in[11];
    const float* thr_h2   = (const float*)d_in[12];
    const float* W_out    = (const float*)d_in[13];
    const float* b_out    = (const float*)d_in[14];
    const float* beta_out = (const float*)d_in[15];
    const float* W_pred   = (const float*)d_in[16];
    const float* b_pred   = (const float*)d_in[17];

    char* ws = (char*)d_ws;
    unsigned short* WA = (unsigned short*)(ws + WS_WA_B);
    float* emb = (float*)(ws + WS_EMB_B);
    float* rec = (float*)(ws + WS_REC_B);

    split_weights_kernel<<<1536, 256, 0, stream>>>(W_h, W_h2, WA);
    setup_emb_kernel<<<1, 64, 0, stream>>>(emb);

    snn_main_kernel<<<NBLK, 512, 0, stream>>>(
        x, W_in, b_in, beta_in, thr_in,
        b_h, beta_h, thr_h,
        b_h2, beta_h2, thr_h2,
        W_out, b_out, beta_out,
        WA, emb, rec);

    pred_kernel<<<BB / 256, 256, 0, stream>>>(rec, W_pred, b_pred, (float*)d_out);
}